// Round 1
// baseline (168.559 us; speedup 1.0000x reference)
//
#include <hip/hip_runtime.h>

#define N_USERS 16384
#define N_MOVIES 8192
#define LATENT 5

constexpr int BLOCK = 256;
constexpr int TU = 64;                 // users per tile
constexpr int MPT = 4;                 // movies per thread (float4 of matrix)
constexpr int TM = BLOCK * MPT;        // 1024 movies per tile
constexpr int MTILES = N_MOVIES / TM;  // 8
constexpr int UTILES = N_USERS / TU;   // 256

__device__ inline float wave_reduce(float v) {
    #pragma unroll
    for (int off = 32; off > 0; off >>= 1)
        v += __shfl_down(v, off, 64);
    return v;
}

__global__ __launch_bounds__(BLOCK) void pmf_err_kernel(
        const float* __restrict__ M, const float* __restrict__ U,
        const float* __restrict__ V, float* __restrict__ out) {
    const int mtile = (int)blockIdx.x % MTILES;
    const int utile = (int)blockIdx.x / MTILES;
    const int m0 = mtile * TM + (int)threadIdx.x * MPT;
    const int u0 = utile * TU;

    // V-features for this thread's 4 movies live in registers for the whole tile.
    float vf[MPT][LATENT];
    #pragma unroll
    for (int j = 0; j < MPT; ++j)
        #pragma unroll
        for (int k = 0; k < LATENT; ++k)
            vf[j][k] = V[(m0 + j) * LATENT + k];

    float acc = 0.f;
    #pragma unroll 4
    for (int uu = 0; uu < TU; ++uu) {
        const int u = u0 + uu;
        const float* uf = &U[u * LATENT];   // wave-uniform -> s_load
        const float u0f = uf[0], u1f = uf[1], u2f = uf[2], u3f = uf[3], u4f = uf[4];
        const float4 mr = *reinterpret_cast<const float4*>(&M[(size_t)u * N_MOVIES + m0]);
        const float mv[MPT] = {mr.x, mr.y, mr.z, mr.w};
        #pragma unroll
        for (int j = 0; j < MPT; ++j) {
            float s = u0f * vf[j][0];
            s = fmaf(u1f, vf[j][1], s);
            s = fmaf(u2f, vf[j][2], s);
            s = fmaf(u3f, vf[j][3], s);
            s = fmaf(u4f, vf[j][4], s);
            float t = __expf(-s);                          // v_exp_f32 path
            float p = __builtin_amdgcn_rcpf(1.0f + t);     // fast rcp, ~1 ulp
            float e = (mv[j] != -1.0f) ? (mv[j] - p) : 0.0f;
            acc = fmaf(e, e, acc);
        }
    }
    acc = wave_reduce(acc);
    if ((threadIdx.x & 63) == 0) atomicAdd(out, acc);
}

__global__ __launch_bounds__(BLOCK) void pmf_reg_kernel(
        const float* __restrict__ U, const float* __restrict__ V,
        float* __restrict__ out) {
    const int idx = (int)blockIdx.x * BLOCK + (int)threadIdx.x;
    float val = 0.f;
    if (idx < N_USERS + N_MOVIES) {
        const float* f = (idx < N_USERS) ? (U + (size_t)idx * LATENT)
                                         : (V + (size_t)(idx - N_USERS) * LATENT);
        float s = 0.f;
        #pragma unroll
        for (int k = 0; k < LATENT; ++k) s = fmaf(f[k], f[k], s);
        val = 0.3f * sqrtf(s);
    }
    val = wave_reduce(val);
    if ((threadIdx.x & 63) == 0) atomicAdd(out, val);
}

extern "C" void kernel_launch(void* const* d_in, const int* in_sizes, int n_in,
                              void* d_out, int out_size, void* d_ws, size_t ws_size,
                              hipStream_t stream) {
    const float* M = (const float*)d_in[0];   // matrix   [16384, 8192]
    const float* U = (const float*)d_in[1];   // user_features  [16384, 5]
    const float* V = (const float*)d_in[2];   // movie_features [8192, 5]
    float* out = (float*)d_out;

    // d_out is poisoned (0xAA) once and never re-poisoned between replays:
    // zero it every call (async memset is graph-capture-safe).
    hipMemsetAsync(out, 0, sizeof(float), stream);

    const int regN = N_USERS + N_MOVIES;
    pmf_reg_kernel<<<(regN + BLOCK - 1) / BLOCK, BLOCK, 0, stream>>>(U, V, out);
    pmf_err_kernel<<<UTILES * MTILES, BLOCK, 0, stream>>>(M, U, V, out);
}

// Round 2
// 146.270 us; speedup vs baseline: 1.1524x; 1.1524x over previous
//
#include <hip/hip_runtime.h>

#define N_USERS 16384
#define N_MOVIES 8192
#define LATENT 5

constexpr int BLOCK = 256;
constexpr int TU = 64;                 // users per tile
constexpr int MPT = 8;                 // movies per thread (2x float4 of matrix)
constexpr int TM = BLOCK * MPT;        // 2048 movies per tile
constexpr int MTILES = N_MOVIES / TM;  // 4
constexpr int UTILES = N_USERS / TU;   // 256

__device__ inline float wave_reduce(float v) {
    #pragma unroll
    for (int off = 32; off > 0; off >>= 1)
        v += __shfl_down(v, off, 64);
    return v;
}

__global__ __launch_bounds__(BLOCK, 4) void pmf_err_kernel(
        const float* __restrict__ M, const float* __restrict__ U,
        const float* __restrict__ V, float* __restrict__ out) {
    __shared__ float uS[TU][LATENT];   // 1.28 KB: user features for this tile

    const int mtile = (int)blockIdx.x % MTILES;
    const int utile = (int)blockIdx.x / MTILES;
    const int tid = (int)threadIdx.x;
    const int u0 = utile * TU;
    const int m0 = mtile * TM + tid * MPT;

    // Stage U tile into LDS (one-time; in-loop reads are uniform-addr broadcasts).
    for (int i = tid; i < TU * LATENT; i += BLOCK)
        uS[i / LATENT][i % LATENT] = U[(size_t)u0 * LATENT + i];
    __syncthreads();

    // This thread's 8 movies' V-features: 40 consecutive floats, 16B-aligned
    // (m0 is a multiple of 8 -> byte offset m0*20 is a multiple of 160).
    float vbuf[MPT * LATENT];
    {
        const float4* vp = reinterpret_cast<const float4*>(&V[(size_t)m0 * LATENT]);
        #pragma unroll
        for (int i = 0; i < MPT * LATENT / 4; ++i)
            reinterpret_cast<float4*>(vbuf)[i] = vp[i];
    }

    float acc0 = 0.f, acc1 = 0.f;

    auto compute = [&](const float4& x0, const float4& x1, const float uc[LATENT]) {
        const float mv[MPT] = {x0.x, x0.y, x0.z, x0.w, x1.x, x1.y, x1.z, x1.w};
        #pragma unroll
        for (int j = 0; j < MPT; ++j) {
            float s = uc[0] * vbuf[j * LATENT + 0];
            s = fmaf(uc[1], vbuf[j * LATENT + 1], s);
            s = fmaf(uc[2], vbuf[j * LATENT + 2], s);
            s = fmaf(uc[3], vbuf[j * LATENT + 3], s);
            s = fmaf(uc[4], vbuf[j * LATENT + 4], s);
            float t = __expf(-s);                       // v_exp_f32 path
            float p = __builtin_amdgcn_rcpf(1.0f + t);  // fast rcp
            float e = (mv[j] != -1.0f) ? (mv[j] - p) : 0.0f;
            if (j & 1) acc1 = fmaf(e, e, acc1);
            else       acc0 = fmaf(e, e, acc0);
        }
    };

    // Software pipeline: row t+1's global loads + U LDS reads issue before
    // row t's compute retires, keeping 2 KB/wave of HBM reads in flight.
    const float* rowp = &M[(size_t)u0 * N_MOVIES + m0];
    float4 ca = *reinterpret_cast<const float4*>(rowp);
    float4 cb = *reinterpret_cast<const float4*>(rowp + 4);
    float uc[LATENT];
    #pragma unroll
    for (int k = 0; k < LATENT; ++k) uc[k] = uS[0][k];

    for (int uu = 0; uu < TU - 1; ++uu) {
        const float* nrow = rowp + N_MOVIES;
        float4 na = *reinterpret_cast<const float4*>(nrow);
        float4 nb = *reinterpret_cast<const float4*>(nrow + 4);
        float un[LATENT];
        #pragma unroll
        for (int k = 0; k < LATENT; ++k) un[k] = uS[uu + 1][k];

        compute(ca, cb, uc);

        ca = na; cb = nb;
        #pragma unroll
        for (int k = 0; k < LATENT; ++k) uc[k] = un[k];
        rowp = nrow;
    }
    compute(ca, cb, uc);   // epilogue row

    float acc = wave_reduce(acc0 + acc1);
    if ((tid & 63) == 0) atomicAdd(out, acc);
}

__global__ __launch_bounds__(BLOCK) void pmf_reg_kernel(
        const float* __restrict__ U, const float* __restrict__ V,
        float* __restrict__ out) {
    const int idx = (int)blockIdx.x * BLOCK + (int)threadIdx.x;
    float val = 0.f;
    if (idx < N_USERS + N_MOVIES) {
        const float* f = (idx < N_USERS) ? (U + (size_t)idx * LATENT)
                                         : (V + (size_t)(idx - N_USERS) * LATENT);
        float s = 0.f;
        #pragma unroll
        for (int k = 0; k < LATENT; ++k) s = fmaf(f[k], f[k], s);
        val = 0.3f * sqrtf(s);
    }
    val = wave_reduce(val);
    if ((threadIdx.x & 63) == 0) atomicAdd(out, val);
}

extern "C" void kernel_launch(void* const* d_in, const int* in_sizes, int n_in,
                              void* d_out, int out_size, void* d_ws, size_t ws_size,
                              hipStream_t stream) {
    const float* M = (const float*)d_in[0];   // matrix        [16384, 8192]
    const float* U = (const float*)d_in[1];   // user_features [16384, 5]
    const float* V = (const float*)d_in[2];   // movie_features [8192, 5]
    float* out = (float*)d_out;

    // d_out is poisoned once and never re-poisoned between replays: zero it
    // every call (async memset is graph-capture-safe).
    hipMemsetAsync(out, 0, sizeof(float), stream);

    const int regN = N_USERS + N_MOVIES;
    pmf_reg_kernel<<<(regN + BLOCK - 1) / BLOCK, BLOCK, 0, stream>>>(U, V, out);
    pmf_err_kernel<<<UTILES * MTILES, BLOCK, 0, stream>>>(M, U, V, out);
}